// Round 1
// baseline (177.731 us; speedup 1.0000x reference)
//
#include <hip/hip_runtime.h>

#define NN 64
#define NITER 20

// One block (64 threads = 1 wave) per (s,t) matrix. Thread m owns row m of
// M = r_const[s,t,:,:] in registers (64 floats). Power-iterate v <- M v from
// LDS double buffer; column-stochastic => sum(v) invariant, no renorm.
__global__ __launch_bounds__(64, 4) void perron_kernel(
    const float* __restrict__ x,
    const float* __restrict__ wt,
    const float* __restrict__ rconst,
    float* __restrict__ ws)
{
    const int st = blockIdx.x;        // 0..4095  (st = s*64 + t)
    const int m  = threadIdx.x;       // 0..63, my row
    const int s  = st >> 6;

    const float* M = rconst + (size_t)st * (NN * NN);   // row-major [m][n]

    // Load my row into registers: 16 x float4 (coalesced within the wave:
    // lane m reads 64B-line m; each line fetched once, later quarters L1-hit).
    float4 row[16];
    const float4* M4 = (const float4*)(M + m * NN);
    #pragma unroll
    for (int q = 0; q < 16; ++q) row[q] = M4[q];

    __shared__ float vbuf[2][NN];
    vbuf[0][m] = 1.0f / NN;
    __syncthreads();

    int cur = 0;
    for (int it = 0; it < NITER; ++it) {
        const float4* v4 = (const float4*)vbuf[cur];
        float acc = 0.0f;
        #pragma unroll
        for (int q = 0; q < 16; ++q) {
            float4 v = v4[q];               // broadcast ds_read_b128
            acc += row[q].x * v.x;
            acc += row[q].y * v.y;
            acc += row[q].z * v.z;
            acc += row[q].w * v.w;
        }
        cur ^= 1;
        vbuf[cur][m] = acc;                 // sum(v) stays 1 automatically
        __syncthreads();
    }

    // coef = x[s,t] * wt[s,t] * M[s][s] / v[s]   (uniform scalar loads)
    const float Mss  = M[s * NN + s];
    const float coef = x[st] * wt[st] * Mss / vbuf[cur][s];
    ws[(size_t)st * NN + m] = coef * vbuf[cur][m];   // coalesced 256B store
}

// out[n] = sum_st ws[st*64 + n]; 1 MB total, L2-resident from kernel 1.
__global__ __launch_bounds__(256) void reduce_kernel(
    const float* __restrict__ ws, float* __restrict__ out)
{
    const int n   = blockIdx.x;    // 0..63
    const int tid = threadIdx.x;   // 0..255
    float acc = 0.0f;
    #pragma unroll
    for (int r = 0; r < 16; ++r)
        acc += ws[(size_t)(tid + 256 * r) * NN + n];

    // wave reduce (64 lanes)
    #pragma unroll
    for (int off = 32; off > 0; off >>= 1)
        acc += __shfl_down(acc, off, 64);

    __shared__ float wsum[4];
    if ((tid & 63) == 0) wsum[tid >> 6] = acc;
    __syncthreads();
    if (tid == 0) out[n] = wsum[0] + wsum[1] + wsum[2] + wsum[3];
}

extern "C" void kernel_launch(void* const* d_in, const int* in_sizes, int n_in,
                              void* d_out, int out_size, void* d_ws, size_t ws_size,
                              hipStream_t stream) {
    const float* x      = (const float*)d_in[0];   // (64,64)
    const float* wt     = (const float*)d_in[1];   // (64,64)
    // d_in[2] = weights_r, d_in[3] = r_zeros: unused (weights_r * 0 == 0)
    const float* rconst = (const float*)d_in[4];   // (64,64,64,64)
    float* out = (float*)d_out;                    // (64,)
    float* ws  = (float*)d_ws;                     // needs 4096*64*4 = 1 MB

    perron_kernel<<<dim3(NN * NN), dim3(NN), 0, stream>>>(x, wt, rconst, ws);
    reduce_kernel<<<dim3(NN), dim3(256), 0, stream>>>(ws, out);
}